// Round 16
// baseline (861.876 us; speedup 1.0000x reference)
//
#include <hip/hip_runtime.h>
#include <hip/hip_bf16.h>

#define VOCAB 32000
#define EMBED 512
#define HIDDEN 1024
#define NB 8
#define NT 256
#define XH_ROWS 16

#define NCH 8        // independent chains (= batch)
#define NMEM 32      // blocks per chain
#define RCOLS 32     // hidden columns per block
#define NBLK_REC 256
#define NBLK_TR 128
#define NBLK_PROJ 250          // 32000 / 128
#define TILES_PER_TR 250       // 32000 transpose tiles / 128 blocks

typedef __attribute__((ext_vector_type(8))) short bf16x8;
typedef __attribute__((ext_vector_type(4))) float f32x4;
typedef __attribute__((ext_vector_type(4))) unsigned u32x4;

#define AS1 __attribute__((address_space(1)))
#define AS3 __attribute__((address_space(3)))

__device__ __forceinline__ unsigned short bf16_bits(float f) {
    __hip_bfloat16 b = __float2bfloat16(f);
    unsigned short s;
    __builtin_memcpy(&s, &b, 2);
    return s;
}
__device__ __forceinline__ float lo16f(unsigned u) { return __uint_as_float(u << 16); }
__device__ __forceinline__ float hi16f(unsigned u) { return __uint_as_float(u & 0xffff0000u); }

// ---------------- xh = emb[x] @ W_xh + b_h  (fp32) ----------------
__global__ __launch_bounds__(256) void k_xh(const int* __restrict__ ids,
                                            const float* __restrict__ emb,
                                            const float* __restrict__ Wxh,
                                            const float* __restrict__ bh,
                                            float* __restrict__ xh) {
    __shared__ alignas(16) float embS[XH_ROWS][EMBED];
    __shared__ int idsS[XH_ROWS];
    const int tid = threadIdx.x;
    const int blk = blockIdx.x;
    if (tid < XH_ROWS) idsS[tid] = ids[blk * XH_ROWS + tid];
    __syncthreads();
    const float4* emb4 = (const float4*)emb;
#pragma unroll
    for (int rep = 0; rep < (XH_ROWS * EMBED / 4) / 256; ++rep) {
        const int lin = rep * 256 + tid;
        const int r = lin >> 7;
        const int e4 = lin & 127;
        *(float4*)&embS[r][e4 * 4] = emb4[(size_t)idsS[r] * (EMBED / 4) + e4];
    }
    __syncthreads();
    float4 acc[XH_ROWS] = {};
    const float4* W4 = (const float4*)Wxh;
    for (int e = 0; e < EMBED; ++e) {
        const float4 w = W4[(size_t)e * (HIDDEN / 4) + tid];
#pragma unroll
        for (int r = 0; r < XH_ROWS; ++r) {
            const float ev = embS[r][e];
            acc[r].x += ev * w.x; acc[r].y += ev * w.y;
            acc[r].z += ev * w.z; acc[r].w += ev * w.w;
        }
    }
    const float4 bv = ((const float4*)bh)[tid];
#pragma unroll
    for (int r = 0; r < XH_ROWS; ++r) {
        float4 o;
        o.x = acc[r].x + bv.x; o.y = acc[r].y + bv.y;
        o.z = acc[r].z + bv.z; o.w = acc[r].w + bv.w;
        ((float4*)xh)[(size_t)(blk * XH_ROWS + r) * (HIDDEN / 4) + tid] = o;
    }
}

// =======================================================================================
// Fused 3-role kernel: [0,256) recurrence | [256,384) W_hy transpose | [384,634) proj
// - rec: r12-verbatim u64 token-in-data protocol (agent atomics); hs written as paired
//   u32 UC stores; epoch flags at t=64/128/192 (ordered by the poll's inherent vmcnt(0))
//   and a DONE flag after an explicit drain.
// - tr: UC u32 Wt stores; per-block flag after vmcnt(0)+barrier.
// - proj: per (c,q) tile gate on epoch flags; A from hs / B from Wt via global_load_lds
//   (cached; first touch is post-gate so L2 fills fresh); m97-style single-buffer loop
//   reusing r12's verified XOR-swizzle staging/fragment idioms.
// Deadlock-free: 634 x 39.2KB = 24.8MB << 41MB chip LDS (pigeonhole: a rec block can
// always be placed); rec depends on nothing else.
// =======================================================================================
__global__ __launch_bounds__(256, 1) void k_fused(const float* __restrict__ Whh,
                                                  const float* __restrict__ xh,
                                                  unsigned long long* __restrict__ hx,
                                                  unsigned* __restrict__ epoch,   // [8][4][32]
                                                  unsigned* __restrict__ trf,     // [128]
                                                  unsigned* __restrict__ hs32,    // hs as u32 pairs
                                                  const float* __restrict__ Why,
                                                  __hip_bfloat16* __restrict__ Wt,
                                                  const float* __restrict__ by,
                                                  float* __restrict__ C) {
    __shared__ alignas(16) float smemF[9808];  // 39.2 KB
    float* xhS = smemF;                        // rec: [NT*RCOLS]
    float* hS  = smemF + 8192;                 // rec: [16*68]
    float* red = smemF + 9280;                 // rec: [16*33]
    const int tid = threadIdx.x;
    const int bid = blockIdx.x;

    // ================= transpose role =================
    if (bid >= NBLK_REC && bid < NBLK_REC + NBLK_TR) {
        const int tb = bid - NBLK_REC;
        const int cc = tid & 31;
        const int r0 = tid >> 5;
        const int tbase = tb * TILES_PER_TR;
        for (int rnd = 0; rnd < (TILES_PER_TR + 7) / 8; ++rnd) {
            const int base = rnd * 8;
            __syncthreads();
#pragma unroll
            for (int u = 0; u < 8; ++u) {
                const int i = base + u;
                if (i < TILES_PER_TR) {
                    const int g = tbase + i;
                    const int n0 = (g % 1000) * 32;
                    const int k0 = (g / 1000) * 32;
                    float* tile = smemF + u * 1056;
#pragma unroll
                    for (int rr = 0; rr < 4; ++rr) {
                        const int r = r0 + rr * 8;
                        tile[cc * 33 + r] = Why[(size_t)(k0 + r) * VOCAB + n0 + cc];
                    }
                }
            }
            __syncthreads();
            // UC u32 paired stores (bypass L2 -> L3-visible for proj role)
#pragma unroll
            for (int u = 0; u < 8; ++u) {
                const int i = base + u;
                if (i < TILES_PER_TR) {
                    const int g = tbase + i;
                    const int n0 = (g % 1000) * 32;
                    const int k0 = (g / 1000) * 32;
                    float* tile = smemF + u * 1056;
                    unsigned* Wt32 = (unsigned*)Wt;
#pragma unroll
                    for (int rep = 0; rep < 2; ++rep) {
                        const int s = rep * 256 + tid;
                        const int n = s >> 4, cp = s & 15;
                        const unsigned lo = (unsigned)bf16_bits(tile[n * 33 + 2 * cp]);
                        const unsigned hi = (unsigned)bf16_bits(tile[n * 33 + 2 * cp + 1]);
                        __hip_atomic_store(&Wt32[(((size_t)(n0 + n) * HIDDEN + k0) >> 1) + cp],
                                           lo | (hi << 16), __ATOMIC_RELAXED,
                                           __HIP_MEMORY_SCOPE_AGENT);
                    }
                }
            }
        }
        asm volatile("s_waitcnt vmcnt(0)" ::: "memory");  // every wave drains its stores
        __syncthreads();
        if (tid == 0)
            __hip_atomic_store(&trf[tb], 1u, __ATOMIC_RELAXED, __HIP_MEMORY_SCOPE_AGENT);
        return;
    }

    // ================= projection role =================
    if (bid >= NBLK_REC + NBLK_TR) {
        const int nn = bid - (NBLK_REC + NBLK_TR);         // 0..249, cols [nn*128, +128)
        unsigned short* Alds = (unsigned short*)smemF;     // 64x64 bf16 = 8 KB
        unsigned short* Blds = Alds + 4096;                // 128x64 bf16 = 16 KB
        const unsigned short* hsu = (const unsigned short*)hs32;
        const unsigned short* Wtu = (const unsigned short*)Wt;
        const int w = tid >> 6;
        const int lane = tid & 63;
        const int fr = lane & 15, fq = lane >> 4;
        // wait for transpose completion (one-time)
        if (tid < NBLK_TR) {
            while (__hip_atomic_load(&trf[tid], __ATOMIC_RELAXED, __HIP_MEMORY_SCOPE_AGENT) == 0u)
                __builtin_amdgcn_s_sleep(16);
        }
        __syncthreads();
        for (int q = 0; q < 4; ++q) {
            for (int ci = 0; ci < 8; ++ci) {
                const int c = (nn + ci) & 7;
                // gate: all 32 members of chain c have finished quarter q
                if (tid < NMEM) {
                    while (__hip_atomic_load(&epoch[(c * 4 + q) * 32 + tid], __ATOMIC_RELAXED,
                                             __HIP_MEMORY_SCOPE_AGENT) == 0u)
                        __builtin_amdgcn_s_sleep(16);
                }
                __syncthreads();
                f32x4 acc[4][2] = {};
                for (int kt = 0; kt < 16; ++kt) {
                    const unsigned short* Ag = hsu + (size_t)(c * NT + q * 64) * HIDDEN + kt * 64;
                    const unsigned short* Bg = Wtu + (size_t)(nn * 128) * HIDDEN + kt * 64;
#pragma unroll
                    for (int s2 = 0; s2 < 2; ++s2) {
                        const int ch = s2 * 256 + tid;
                        const int row = ch >> 3, ss = (ch & 7) ^ (row & 7);
                        __builtin_amdgcn_global_load_lds(
                            (const AS1 unsigned*)(Ag + (size_t)row * HIDDEN + ss * 8),
                            (AS3 unsigned*)(Alds + (s2 * 256 + w * 64) * 8), 16, 0, 0);
                    }
#pragma unroll
                    for (int s2 = 0; s2 < 4; ++s2) {
                        const int ch = s2 * 256 + tid;
                        const int row = ch >> 3, ss = (ch & 7) ^ (row & 7);
                        __builtin_amdgcn_global_load_lds(
                            (const AS1 unsigned*)(Bg + (size_t)row * HIDDEN + ss * 8),
                            (AS3 unsigned*)(Blds + (s2 * 256 + w * 64) * 8), 16, 0, 0);
                    }
                    asm volatile("s_waitcnt vmcnt(0)" ::: "memory");
                    __syncthreads();
                    bf16x8 af[4][2], bf[2][2];
#pragma unroll
                    for (int mi = 0; mi < 4; ++mi) {
                        const int ra = mi * 16 + fr;
#pragma unroll
                        for (int ks = 0; ks < 2; ++ks)
                            af[mi][ks] = *(const bf16x8*)&Alds[ra * 64 + (((ks * 4 + fq) ^ (fr & 7)) * 8)];
                    }
#pragma unroll
                    for (int ni = 0; ni < 2; ++ni) {
                        const int rb = w * 32 + ni * 16 + fr;
#pragma unroll
                        for (int ks = 0; ks < 2; ++ks)
                            bf[ni][ks] = *(const bf16x8*)&Blds[rb * 64 + (((ks * 4 + fq) ^ (fr & 7)) * 8)];
                    }
#pragma unroll
                    for (int mi = 0; mi < 4; ++mi)
#pragma unroll
                        for (int ni = 0; ni < 2; ++ni) {
                            acc[mi][ni] = __builtin_amdgcn_mfma_f32_16x16x32_bf16(af[mi][0], bf[ni][0], acc[mi][ni], 0, 0, 0);
                            acc[mi][ni] = __builtin_amdgcn_mfma_f32_16x16x32_bf16(af[mi][1], bf[ni][1], acc[mi][ni], 0, 0, 0);
                        }
                    __syncthreads();
                }
                const int m0 = c * NT + q * 64;
#pragma unroll
                for (int ni = 0; ni < 2; ++ni) {
                    const int col = nn * 128 + w * 32 + ni * 16 + fr;
                    const float bias = by[col];
#pragma unroll
                    for (int mi = 0; mi < 4; ++mi) {
                        const int row = m0 + mi * 16 + fq * 4;
                        float* cp = C + (size_t)row * VOCAB + col;
                        cp[0]                 = acc[mi][ni][0] + bias;
                        cp[(size_t)VOCAB]     = acc[mi][ni][1] + bias;
                        cp[(size_t)2 * VOCAB] = acc[mi][ni][2] + bias;
                        cp[(size_t)3 * VOCAB] = acc[mi][ni][3] + bias;
                    }
                }
            }
        }
        return;
    }

    // ================= recurrence role (r12-verbatim protocol) =================
    const int c = bid & (NCH - 1);
    const int m = bid >> 3;
    const int j0 = m * RCOLS;
    unsigned long long* hxc = hx + (size_t)c * 1024;

    const int col2 = tid & 15;
    const int part = tid >> 4;

    u32x4 wreg[16];
#pragma unroll
    for (int j = 0; j < 16; ++j) {
        u32x4 q;
#pragma unroll
        for (int e = 0; e < 4; ++e) {
            const int i = part * 64 + 4 * j + e;
            const float2 wv = *(const float2*)&Whh[(size_t)i * HIDDEN + j0 + 2 * col2];
            q[e] = (unsigned)bf16_bits(wv.x) | ((unsigned)bf16_bits(wv.y) << 16);
        }
        wreg[j] = q;
    }
    for (int idx = tid; idx < NT * RCOLS; idx += 256) {
        const int t = idx >> 5;
        const int col = idx & 31;
        xhS[idx] = xh[(size_t)(c * NT + t) * HIDDEN + j0 + col];
    }
    __syncthreads();

    const f32x4* hv4 = (const f32x4*)&hS[part * 68];
    const int w0 = tid;
    const int w1 = tid + 256;
    const int pe0 = 2 * tid + 4 * (tid >> 5);

    for (int t = 0; t < NT; ++t) {
        unsigned long long* rbuf = hxc + ((t + 1) & 1) * 512;
        unsigned long long* wbuf = hxc + (t & 1) * 512;
        const unsigned long long tok = (unsigned long long)(unsigned)t;
        unsigned long long a = __hip_atomic_load(&rbuf[w0], __ATOMIC_RELAXED, __HIP_MEMORY_SCOPE_AGENT);
        unsigned long long b = __hip_atomic_load(&rbuf[w1], __ATOMIC_RELAXED, __HIP_MEMORY_SCOPE_AGENT);
        while (((a & 0xffffull) != tok) | ((b & 0xffffull) != tok)) {
            __builtin_amdgcn_s_sleep(1);
            if ((a & 0xffffull) != tok)
                a = __hip_atomic_load(&rbuf[w0], __ATOMIC_RELAXED, __HIP_MEMORY_SCOPE_AGENT);
            if ((b & 0xffffull) != tok)
                b = __hip_atomic_load(&rbuf[w1], __ATOMIC_RELAXED, __HIP_MEMORY_SCOPE_AGENT);
        }
        // epoch flags: this wave's poll above forced vmcnt(0), draining all prior
        // hs/hx stores (steps <= t-1) to the coherence point.
        if (tid == 0 && t != 0 && (t & 63) == 0)
            __hip_atomic_store(&epoch[(c * 4 + (t >> 6) - 1) * 32 + m], 1u,
                               __ATOMIC_RELAXED, __HIP_MEMORY_SCOPE_AGENT);
        *(float2*)&hS[pe0] = make_float2(__uint_as_float(((unsigned)(a >> 16) & 0xffffu) << 16),
                                         __uint_as_float(((unsigned)(a >> 32) & 0xffffu) << 16));
        *(float2*)&hS[pe0 + 544] = make_float2(__uint_as_float(((unsigned)(b >> 16) & 0xffffu) << 16),
                                               __uint_as_float(((unsigned)(b >> 32) & 0xffffu) << 16));
        __syncthreads();
        float a0 = 0.f, a1 = 0.f;
#pragma unroll
        for (int j = 0; j < 16; ++j) {
            const u32x4 w4 = wreg[j];
            const f32x4 h4 = hv4[j];
            a0 = fmaf(lo16f(w4.x), h4.x, a0); a1 = fmaf(hi16f(w4.x), h4.x, a1);
            a0 = fmaf(lo16f(w4.y), h4.y, a0); a1 = fmaf(hi16f(w4.y), h4.y, a1);
            a0 = fmaf(lo16f(w4.z), h4.z, a0); a1 = fmaf(hi16f(w4.z), h4.z, a1);
            a0 = fmaf(lo16f(w4.w), h4.w, a0); a1 = fmaf(hi16f(w4.w), h4.w, a1);
        }
        red[part * 33 + 2 * col2]     = a0;
        red[part * 33 + 2 * col2 + 1] = a1;
        __syncthreads();
        if (tid < RCOLS) {
            float s = 0.f;
#pragma unroll
            for (int p = 0; p < 16; ++p) s += red[p * 33 + tid];
            const float v = tanhf(xhS[t * RCOLS + tid] + s);
            const unsigned hb = (unsigned)bf16_bits(v);
            const unsigned pb = (unsigned)__shfl_xor((int)hb, 1, 64);
            if ((tid & 1) == 0) {
                __hip_atomic_store(&hs32[((size_t)(c * NT + t) * HIDDEN + j0 + tid) >> 1],
                                   hb | (pb << 16), __ATOMIC_RELAXED, __HIP_MEMORY_SCOPE_AGENT);
                const unsigned long long wv = (unsigned long long)(unsigned)(t + 1)
                                            | ((unsigned long long)hb << 16)
                                            | ((unsigned long long)pb << 32);
                __hip_atomic_store(&wbuf[m * 16 + (tid >> 1)], wv, __ATOMIC_RELAXED,
                                   __HIP_MEMORY_SCOPE_AGENT);
            }
        }
        asm volatile("" ::: "memory");   // keep next-iter polls after this step's stores
    }
    // final quarter: drain then DONE
    asm volatile("s_waitcnt vmcnt(0)" ::: "memory");
    __syncthreads();
    if (tid == 0)
        __hip_atomic_store(&epoch[(c * 4 + 3) * 32 + m], 1u, __ATOMIC_RELAXED,
                           __HIP_MEMORY_SCOPE_AGENT);
}

extern "C" void kernel_launch(void* const* d_in, const int* in_sizes, int n_in,
                              void* d_out, int out_size, void* d_ws, size_t ws_size,
                              hipStream_t stream) {
    const int*   x   = (const int*)d_in[0];
    const float* emb = (const float*)d_in[1];
    const float* Wxh = (const float*)d_in[2];
    const float* Whh = (const float*)d_in[3];
    const float* bh  = (const float*)d_in[4];
    const float* Why = (const float*)d_in[5];
    const float* by  = (const float*)d_in[6];
    float* y = (float*)d_out;

    char* ws = (char*)d_ws;
    // layout: xh 8MB | hx 64KB + epoch 4KB + trf 0.5KB (in a 128KB cleared region)
    //         | hs u32 4MB | Wt bf16 62.5MB
    const size_t off_xh = 0;
    const size_t off_hx = off_xh + (size_t)NB * NT * HIDDEN * 4;
    const size_t off_ep = off_hx + (size_t)NCH * 2 * 512 * 8;        // +64 KB
    const size_t off_tf = off_ep + 8 * 4 * 32 * 4;                   // +4 KB
    const size_t off_hs = off_hx + 0x20000;                          // 128 KB region
    const size_t off_wt = off_hs + (size_t)NB * NT * HIDDEN * 2;
    const size_t need   = off_wt + (size_t)VOCAB * HIDDEN * 2;
    if (ws_size < need) return;

    float* xh = (float*)(ws + off_xh);
    unsigned long long* hx = (unsigned long long*)(ws + off_hx);
    unsigned* epoch = (unsigned*)(ws + off_ep);
    unsigned* trf = (unsigned*)(ws + off_tf);
    unsigned* hs32 = (unsigned*)(ws + off_hs);
    __hip_bfloat16* Wt = (__hip_bfloat16*)(ws + off_wt);

    // honest re-init every call: tokens/epochs/flags zeroed (token 0 == h_{-1}=0 init)
    hipMemsetAsync(ws + off_hx, 0, 0x20000, stream);
    k_xh<<<dim3((NB * NT) / XH_ROWS), 256, 0, stream>>>(x, emb, Wxh, bh, xh);
    k_fused<<<dim3(NBLK_REC + NBLK_TR + NBLK_PROJ), 256, 0, stream>>>(
        Whh, xh, hx, epoch, trf, hs32, Why, Wt, by, y);
}

// Round 17
// 798.035 us; speedup vs baseline: 1.0800x; 1.0800x over previous
//
#include <hip/hip_runtime.h>
#include <hip/hip_bf16.h>

#define VOCAB 32000
#define EMBED 512
#define HIDDEN 1024
#define NB 8
#define NT 256
#define XH_ROWS 16

#define NCH 8        // independent chains (= batch)
#define NMEM 32      // blocks per chain
#define RCOLS 32     // hidden columns per block
#define NBLK_REC 256
#define NBLK_TR 128
#define TILES_PER_TR 250   // 32000 tiles / 128 blocks

typedef __attribute__((ext_vector_type(8))) short bf16x8;
typedef __attribute__((ext_vector_type(4))) float f32x4;
typedef __attribute__((ext_vector_type(4))) unsigned u32x4;

#define AS1 __attribute__((address_space(1)))
#define AS3 __attribute__((address_space(3)))

__device__ __forceinline__ unsigned short bf16_bits(float f) {
    __hip_bfloat16 b = __float2bfloat16(f);
    unsigned short s;
    __builtin_memcpy(&s, &b, 2);
    return s;
}
__device__ __forceinline__ float lo16f(unsigned u) { return __uint_as_float(u << 16); }
__device__ __forceinline__ float hi16f(unsigned u) { return __uint_as_float(u & 0xffff0000u); }

// ---------------- xh = emb[x] @ W_xh + b_h  (fp32) ----------------
__global__ __launch_bounds__(256) void k_xh(const int* __restrict__ ids,
                                            const float* __restrict__ emb,
                                            const float* __restrict__ Wxh,
                                            const float* __restrict__ bh,
                                            float* __restrict__ xh) {
    __shared__ alignas(16) float embS[XH_ROWS][EMBED];
    __shared__ int idsS[XH_ROWS];
    const int tid = threadIdx.x;
    const int blk = blockIdx.x;
    if (tid < XH_ROWS) idsS[tid] = ids[blk * XH_ROWS + tid];
    __syncthreads();
    const float4* emb4 = (const float4*)emb;
#pragma unroll
    for (int rep = 0; rep < (XH_ROWS * EMBED / 4) / 256; ++rep) {
        const int lin = rep * 256 + tid;
        const int r = lin >> 7;
        const int e4 = lin & 127;
        *(float4*)&embS[r][e4 * 4] = emb4[(size_t)idsS[r] * (EMBED / 4) + e4];
    }
    __syncthreads();
    float4 acc[XH_ROWS] = {};
    const float4* W4 = (const float4*)Wxh;
    for (int e = 0; e < EMBED; ++e) {
        const float4 w = W4[(size_t)e * (HIDDEN / 4) + tid];
#pragma unroll
        for (int r = 0; r < XH_ROWS; ++r) {
            const float ev = embS[r][e];
            acc[r].x += ev * w.x; acc[r].y += ev * w.y;
            acc[r].z += ev * w.z; acc[r].w += ev * w.w;
        }
    }
    const float4 bv = ((const float4*)bh)[tid];
#pragma unroll
    for (int r = 0; r < XH_ROWS; ++r) {
        float4 o;
        o.x = acc[r].x + bv.x; o.y = acc[r].y + bv.y;
        o.z = acc[r].z + bv.z; o.w = acc[r].w + bv.w;
        ((float4*)xh)[(size_t)(blk * XH_ROWS + r) * (HIDDEN / 4) + tid] = o;
    }
}

// ---------------- fused persistent recurrence + W_hy transpose (r15 verbatim) ----------------
__global__ __launch_bounds__(256, 1) void k_fused(const float* __restrict__ Whh,
                                                  const float* __restrict__ xh,
                                                  unsigned long long* __restrict__ hx,
                                                  __hip_bfloat16* __restrict__ hs,
                                                  const float* __restrict__ Why,
                                                  __hip_bfloat16* __restrict__ Wt) {
    __shared__ alignas(16) float smemF[9808];  // 39.2 KB
    float* xhS = smemF;
    float* hS  = smemF + 8192;
    float* red = smemF + 9280;
    const int tid = threadIdx.x;
    const int bid = blockIdx.x;

    if (bid >= NBLK_REC) {
        // ---- transpose role: 8 tiles (32x33 f32) per round, cached stores ----
        const int tb = bid - NBLK_REC;
        const int cc = tid & 31;
        const int r0 = tid >> 5;
        const int tbase = tb * TILES_PER_TR;
        for (int rnd = 0; rnd < (TILES_PER_TR + 7) / 8; ++rnd) {
            const int base = rnd * 8;
            __syncthreads();
#pragma unroll
            for (int u = 0; u < 8; ++u) {
                const int i = base + u;
                if (i < TILES_PER_TR) {
                    const int g = tbase + i;
                    const int n0 = (g % 1000) * 32;
                    const int k0 = (g / 1000) * 32;
                    float* tile = smemF + u * 1056;
#pragma unroll
                    for (int rr = 0; rr < 4; ++rr) {
                        const int r = r0 + rr * 8;
                        tile[cc * 33 + r] = Why[(size_t)(k0 + r) * VOCAB + n0 + cc];
                    }
                }
            }
            __syncthreads();
#pragma unroll
            for (int u = 0; u < 8; ++u) {
                const int i = base + u;
                if (i < TILES_PER_TR) {
                    const int g = tbase + i;
                    const int n0 = (g % 1000) * 32;
                    const int k0 = (g / 1000) * 32;
                    float* tile = smemF + u * 1056;
#pragma unroll
                    for (int rr = 0; rr < 4; ++rr) {
                        const int n = r0 + rr * 8;
                        Wt[(size_t)(n0 + n) * HIDDEN + k0 + cc] = __float2bfloat16(tile[n * 33 + cc]);
                    }
                }
            }
        }
        return;
    }

    // ---- recurrence role (round-12 verbatim protocol) ----
    const int c = bid & (NCH - 1);
    const int m = bid >> 3;
    const int j0 = m * RCOLS;
    unsigned long long* hxc = hx + (size_t)c * 1024;

    if (tid < 16)
        __hip_atomic_store(&hxc[512 + m * 16 + tid], 0ull, __ATOMIC_RELAXED,
                           __HIP_MEMORY_SCOPE_AGENT);

    const int col2 = tid & 15;
    const int part = tid >> 4;

    u32x4 wreg[16];
#pragma unroll
    for (int j = 0; j < 16; ++j) {
        u32x4 q;
#pragma unroll
        for (int e = 0; e < 4; ++e) {
            const int i = part * 64 + 4 * j + e;
            const float2 wv = *(const float2*)&Whh[(size_t)i * HIDDEN + j0 + 2 * col2];
            q[e] = (unsigned)bf16_bits(wv.x) | ((unsigned)bf16_bits(wv.y) << 16);
        }
        wreg[j] = q;
    }
    for (int idx = tid; idx < NT * RCOLS; idx += 256) {
        const int t = idx >> 5;
        const int col = idx & 31;
        xhS[idx] = xh[(size_t)(c * NT + t) * HIDDEN + j0 + col];
    }
    __syncthreads();

    const f32x4* hv4 = (const f32x4*)&hS[part * 68];
    const int w0 = tid;
    const int w1 = tid + 256;
    const int pe0 = 2 * tid + 4 * (tid >> 5);

    for (int t = 0; t < NT; ++t) {
        unsigned long long* rbuf = hxc + ((t + 1) & 1) * 512;
        unsigned long long* wbuf = hxc + (t & 1) * 512;
        const unsigned long long tok = (unsigned long long)(unsigned)t;
        unsigned long long a = __hip_atomic_load(&rbuf[w0], __ATOMIC_RELAXED, __HIP_MEMORY_SCOPE_AGENT);
        unsigned long long b = __hip_atomic_load(&rbuf[w1], __ATOMIC_RELAXED, __HIP_MEMORY_SCOPE_AGENT);
        while (((a & 0xffffull) != tok) | ((b & 0xffffull) != tok)) {
            __builtin_amdgcn_s_sleep(1);
            if ((a & 0xffffull) != tok)
                a = __hip_atomic_load(&rbuf[w0], __ATOMIC_RELAXED, __HIP_MEMORY_SCOPE_AGENT);
            if ((b & 0xffffull) != tok)
                b = __hip_atomic_load(&rbuf[w1], __ATOMIC_RELAXED, __HIP_MEMORY_SCOPE_AGENT);
        }
        *(float2*)&hS[pe0] = make_float2(__uint_as_float(((unsigned)(a >> 16) & 0xffffu) << 16),
                                         __uint_as_float(((unsigned)(a >> 32) & 0xffffu) << 16));
        *(float2*)&hS[pe0 + 544] = make_float2(__uint_as_float(((unsigned)(b >> 16) & 0xffffu) << 16),
                                               __uint_as_float(((unsigned)(b >> 32) & 0xffffu) << 16));
        __syncthreads();
        float a0 = 0.f, a1 = 0.f;
#pragma unroll
        for (int j = 0; j < 16; ++j) {
            const u32x4 w4 = wreg[j];
            const f32x4 h4 = hv4[j];
            a0 = fmaf(lo16f(w4.x), h4.x, a0); a1 = fmaf(hi16f(w4.x), h4.x, a1);
            a0 = fmaf(lo16f(w4.y), h4.y, a0); a1 = fmaf(hi16f(w4.y), h4.y, a1);
            a0 = fmaf(lo16f(w4.z), h4.z, a0); a1 = fmaf(hi16f(w4.z), h4.z, a1);
            a0 = fmaf(lo16f(w4.w), h4.w, a0); a1 = fmaf(hi16f(w4.w), h4.w, a1);
        }
        red[part * 33 + 2 * col2]     = a0;
        red[part * 33 + 2 * col2 + 1] = a1;
        __syncthreads();
        if (tid < RCOLS) {
            float s = 0.f;
#pragma unroll
            for (int p = 0; p < 16; ++p) s += red[p * 33 + tid];
            const float v = tanhf(xhS[t * RCOLS + tid] + s);
            const unsigned hb = (unsigned)bf16_bits(v);
            ((unsigned short*)hs)[(size_t)(c * NT + t) * HIDDEN + j0 + tid] = (unsigned short)hb;
            const unsigned pb = (unsigned)__shfl_xor((int)hb, 1, 64);
            if ((tid & 1) == 0) {
                const unsigned long long wv = (unsigned long long)(unsigned)(t + 1)
                                            | ((unsigned long long)hb << 16)
                                            | ((unsigned long long)pb << 32);
                __hip_atomic_store(&wbuf[m * 16 + (tid >> 1)], wv, __ATOMIC_RELAXED,
                                   __HIP_MEMORY_SCOPE_AGENT);
            }
        }
    }
}

// ---------------- y = hs @ Wt^T + b_y : 256x256, BK=32, 2 blocks/CU ----------------
// LDS 64KB (2buf x 2mat x 256x32 bf16) -> 2 blocks/CU: implicit cross-block wave
// overlap (m114) hides the per-tile barrier drains the 1-block/CU version exposed.
// Counted vmcnt(4) keeps next tile's 4 loads in flight; linear-dest global_load_lds
// with inverse-XOR source; read slot = fq ^ ((row>>1)&3) -> 2-way banks (free).
__global__ __launch_bounds__(512, 2) void k_proj(const unsigned short* __restrict__ A,   // [2048][1024]
                                                 const unsigned short* __restrict__ Bt,  // [32000][1024]
                                                 const float* __restrict__ by,
                                                 float* __restrict__ C) {
    __shared__ unsigned short LDS[2][2][8192];   // [buf][mat][256*32] bf16 = 64 KB
    const int tid = threadIdx.x;
    const int wid = tid >> 6;
    const int lane = tid & 63;
    const int lin = blockIdx.x;
    // bijective XCD swizzle (1000 % 8 == 0), mt fastest within an XCD chunk
    const int swz = (lin & 7) * 125 + (lin >> 3);
    const int mt = swz & 7, nt = swz >> 3;
    const int m0 = mt * 256, n0 = nt * 256;
    const int wr = wid >> 2, wc = wid & 3;       // 2 x 4 wave grid
    const int fr = lane & 15, fq = lane >> 4;

    f32x4 acc[8][4] = {};

#define STAGE(kt, bf)                                                                     \
    {                                                                                     \
        const unsigned short* Ag = A + (size_t)m0 * HIDDEN + (size_t)(kt) * 32;           \
        const unsigned short* Bg = Bt + (size_t)n0 * HIDDEN + (size_t)(kt) * 32;          \
        _Pragma("unroll")                                                                 \
        for (int s2 = 0; s2 < 2; ++s2) {                                                  \
            const int ch = s2 * 512 + tid;                                                \
            const int row = ch >> 2, sp = ch & 3;                                         \
            const int gs = sp ^ ((row >> 1) & 3);                                         \
            __builtin_amdgcn_global_load_lds(                                             \
                (const AS1 unsigned*)(Ag + (size_t)row * HIDDEN + gs * 8),                \
                (AS3 unsigned*)(&LDS[bf][0][(s2 * 512 + wid * 64) * 8]), 16, 0, 0);       \
        }                                                                                 \
        _Pragma("unroll")                                                                 \
        for (int s2 = 0; s2 < 2; ++s2) {                                                  \
            const int ch = s2 * 512 + tid;                                                \
            const int row = ch >> 2, sp = ch & 3;                                         \
            const int gs = sp ^ ((row >> 1) & 3);                                         \
            __builtin_amdgcn_global_load_lds(                                             \
                (const AS1 unsigned*)(Bg + (size_t)row * HIDDEN + gs * 8),                \
                (AS3 unsigned*)(&LDS[bf][1][(s2 * 512 + wid * 64) * 8]), 16, 0, 0);       \
        }                                                                                 \
    }

    STAGE(0, 0);
    STAGE(1, 1);

    int cur = 0;
    for (int kt = 0; kt < 32; ++kt) {
        if (kt < 31) { asm volatile("s_waitcnt vmcnt(4)" ::: "memory"); }
        else         { asm volatile("s_waitcnt vmcnt(0)" ::: "memory"); }
        __builtin_amdgcn_s_barrier();            // tile bf=cur fully visible

        const unsigned short* Ab = &LDS[cur][0][0];
        const unsigned short* Bb = &LDS[cur][1][0];
        bf16x8 af[8], bg[4];
#pragma unroll
        for (int mi = 0; mi < 8; ++mi) {
            const int ra = wr * 128 + mi * 16 + fr;
            af[mi] = *(const bf16x8*)&Ab[ra * 32 + ((fq ^ ((ra >> 1) & 3)) * 8)];
        }
#pragma unroll
        for (int ni = 0; ni < 4; ++ni) {
            const int rb = wc * 64 + ni * 16 + fr;
            bg[ni] = *(const bf16x8*)&Bb[rb * 32 + ((fq ^ ((rb >> 1) & 3)) * 8)];
        }
        asm volatile("s_waitcnt lgkmcnt(0)" ::: "memory");
        __builtin_amdgcn_sched_barrier(0);
        __builtin_amdgcn_s_barrier();            // all waves done reading bf=cur

        if (kt < 30) STAGE(kt + 2, cur);         // refill freed buffer; stays in flight

        __builtin_amdgcn_s_setprio(1);
#pragma unroll
        for (int mi = 0; mi < 8; ++mi)
#pragma unroll
            for (int ni = 0; ni < 4; ++ni)
                acc[mi][ni] = __builtin_amdgcn_mfma_f32_16x16x32_bf16(af[mi], bg[ni], acc[mi][ni], 0, 0, 0);
        __builtin_amdgcn_s_setprio(0);
        cur ^= 1;
    }
#undef STAGE

#pragma unroll
    for (int ni = 0; ni < 4; ++ni) {
        const int col = n0 + wc * 64 + ni * 16 + fr;
        const float bias = by[col];
#pragma unroll
        for (int mi = 0; mi < 8; ++mi) {
            const int row = m0 + wr * 128 + mi * 16 + fq * 4;
            float* cp = C + (size_t)row * VOCAB + col;
            cp[0]                 = acc[mi][ni][0] + bias;
            cp[(size_t)VOCAB]     = acc[mi][ni][1] + bias;
            cp[(size_t)2 * VOCAB] = acc[mi][ni][2] + bias;
            cp[(size_t)3 * VOCAB] = acc[mi][ni][3] + bias;
        }
    }
}

extern "C" void kernel_launch(void* const* d_in, const int* in_sizes, int n_in,
                              void* d_out, int out_size, void* d_ws, size_t ws_size,
                              hipStream_t stream) {
    const int*   x   = (const int*)d_in[0];
    const float* emb = (const float*)d_in[1];
    const float* Wxh = (const float*)d_in[2];
    const float* Whh = (const float*)d_in[3];
    const float* bh  = (const float*)d_in[4];
    const float* Why = (const float*)d_in[5];
    const float* by  = (const float*)d_in[6];
    float* y = (float*)d_out;

    char* ws = (char*)d_ws;
    // layout: xh (8 MB) | hx u64[8][2][512] (64 KB) | hs bf16 (4 MB) | Wt bf16 (62.5 MB)
    const size_t off_xh = 0;
    const size_t off_hx = off_xh + (size_t)NB * NT * HIDDEN * 4;
    const size_t off_hs = off_hx + (size_t)NCH * 2 * 512 * 8;
    const size_t off_wt = off_hs + (size_t)NB * NT * HIDDEN * 2;
    const size_t need   = off_wt + (size_t)VOCAB * HIDDEN * 2;
    if (ws_size < need) return;

    float* xh = (float*)(ws + off_xh);
    unsigned long long* hx = (unsigned long long*)(ws + off_hx);
    __hip_bfloat16* hs = (__hip_bfloat16*)(ws + off_hs);
    __hip_bfloat16* Wt = (__hip_bfloat16*)(ws + off_wt);

    k_xh<<<dim3((NB * NT) / XH_ROWS), 256, 0, stream>>>(x, emb, Wxh, bh, xh);
    k_fused<<<dim3(NBLK_REC + NBLK_TR), 256, 0, stream>>>(Whh, xh, hx, hs, Why, Wt);
    k_proj<<<dim3((2048 / 256) * (VOCAB / 256)), 512, 0, stream>>>((const unsigned short*)hs,
                                                                   (const unsigned short*)Wt, by, y);
}

// Round 19
// 789.114 us; speedup vs baseline: 1.0922x; 1.0113x over previous
//
#include <hip/hip_runtime.h>
#include <hip/hip_bf16.h>

#define VOCAB 32000
#define EMBED 512
#define HIDDEN 1024
#define NB 8
#define NT 256
#define XH_ROWS 16

#define NCH 8
#define NMEM 32
#define RCOLS 32
#define NBLK_REC 256
#define NBLK_TR 128
#define TILES_PER_TR 250

typedef __attribute__((ext_vector_type(8))) short bf16x8;
typedef __attribute__((ext_vector_type(4))) float f32x4;
typedef __attribute__((ext_vector_type(4))) unsigned u32x4;

#define AS1 __attribute__((address_space(1)))
#define AS3 __attribute__((address_space(3)))

__device__ __forceinline__ unsigned short bf16_bits(float f) {
    __hip_bfloat16 b = __float2bfloat16(f);
    unsigned short s;
    __builtin_memcpy(&s, &b, 2);
    return s;
}
__device__ __forceinline__ float lo16f(unsigned u) { return __uint_as_float(u << 16); }
__device__ __forceinline__ float hi16f(unsigned u) { return __uint_as_float(u & 0xffff0000u); }

// ---------------- xh = emb[x] @ W_xh + b_h  (fp32) ----------------
__global__ __launch_bounds__(256) void k_xh(const int* __restrict__ ids,
                                            const float* __restrict__ emb,
                                            const float* __restrict__ Wxh,
                                            const float* __restrict__ bh,
                                            float* __restrict__ xh) {
    __shared__ alignas(16) float embS[XH_ROWS][EMBED];
    __shared__ int idsS[XH_ROWS];
    const int tid = threadIdx.x;
    const int blk = blockIdx.x;
    if (tid < XH_ROWS) idsS[tid] = ids[blk * XH_ROWS + tid];
    __syncthreads();
    const float4* emb4 = (const float4*)emb;
#pragma unroll
    for (int rep = 0; rep < (XH_ROWS * EMBED / 4) / 256; ++rep) {
        const int lin = rep * 256 + tid;
        const int r = lin >> 7;
        const int e4 = lin & 127;
        *(float4*)&embS[r][e4 * 4] = emb4[(size_t)idsS[r] * (EMBED / 4) + e4];
    }
    __syncthreads();
    float4 acc[XH_ROWS] = {};
    const float4* W4 = (const float4*)Wxh;
    for (int e = 0; e < EMBED; ++e) {
        const float4 w = W4[(size_t)e * (HIDDEN / 4) + tid];
#pragma unroll
        for (int r = 0; r < XH_ROWS; ++r) {
            const float ev = embS[r][e];
            acc[r].x += ev * w.x; acc[r].y += ev * w.y;
            acc[r].z += ev * w.z; acc[r].w += ev * w.w;
        }
    }
    const float4 bv = ((const float4*)bh)[tid];
#pragma unroll
    for (int r = 0; r < XH_ROWS; ++r) {
        float4 o;
        o.x = acc[r].x + bv.x; o.y = acc[r].y + bv.y;
        o.z = acc[r].z + bv.z; o.w = acc[r].w + bv.w;
        ((float4*)xh)[(size_t)(blk * XH_ROWS + r) * (HIDDEN / 4) + tid] = o;
    }
}

// ---------------- fused persistent recurrence + W_hy transpose (r15 verbatim) ----------------
__global__ __launch_bounds__(256, 1) void k_fused(const float* __restrict__ Whh,
                                                  const float* __restrict__ xh,
                                                  unsigned long long* __restrict__ hx,
                                                  __hip_bfloat16* __restrict__ hs,
                                                  const float* __restrict__ Why,
                                                  __hip_bfloat16* __restrict__ Wt) {
    __shared__ alignas(16) float smemF[9808];
    float* xhS = smemF;
    float* hS  = smemF + 8192;
    float* red = smemF + 9280;
    const int tid = threadIdx.x;
    const int bid = blockIdx.x;

    if (bid >= NBLK_REC) {
        const int tb = bid - NBLK_REC;
        const int cc = tid & 31;
        const int r0 = tid >> 5;
        const int tbase = tb * TILES_PER_TR;
        for (int rnd = 0; rnd < (TILES_PER_TR + 7) / 8; ++rnd) {
            const int base = rnd * 8;
            __syncthreads();
#pragma unroll
            for (int u = 0; u < 8; ++u) {
                const int i = base + u;
                if (i < TILES_PER_TR) {
                    const int g = tbase + i;
                    const int n0 = (g % 1000) * 32;
                    const int k0 = (g / 1000) * 32;
                    float* tile = smemF + u * 1056;
#pragma unroll
                    for (int rr = 0; rr < 4; ++rr) {
                        const int r = r0 + rr * 8;
                        tile[cc * 33 + r] = Why[(size_t)(k0 + r) * VOCAB + n0 + cc];
                    }
                }
            }
            __syncthreads();
#pragma unroll
            for (int u = 0; u < 8; ++u) {
                const int i = base + u;
                if (i < TILES_PER_TR) {
                    const int g = tbase + i;
                    const int n0 = (g % 1000) * 32;
                    const int k0 = (g / 1000) * 32;
                    float* tile = smemF + u * 1056;
#pragma unroll
                    for (int rr = 0; rr < 4; ++rr) {
                        const int n = r0 + rr * 8;
                        Wt[(size_t)(n0 + n) * HIDDEN + k0 + cc] = __float2bfloat16(tile[n * 33 + cc]);
                    }
                }
            }
        }
        return;
    }

    const int c = bid & (NCH - 1);
    const int m = bid >> 3;
    const int j0 = m * RCOLS;
    unsigned long long* hxc = hx + (size_t)c * 1024;

    if (tid < 16)
        __hip_atomic_store(&hxc[512 + m * 16 + tid], 0ull, __ATOMIC_RELAXED,
                           __HIP_MEMORY_SCOPE_AGENT);

    const int col2 = tid & 15;
    const int part = tid >> 4;

    u32x4 wreg[16];
#pragma unroll
    for (int j = 0; j < 16; ++j) {
        u32x4 q;
#pragma unroll
        for (int e = 0; e < 4; ++e) {
            const int i = part * 64 + 4 * j + e;
            const float2 wv = *(const float2*)&Whh[(size_t)i * HIDDEN + j0 + 2 * col2];
            q[e] = (unsigned)bf16_bits(wv.x) | ((unsigned)bf16_bits(wv.y) << 16);
        }
        wreg[j] = q;
    }
    for (int idx = tid; idx < NT * RCOLS; idx += 256) {
        const int t = idx >> 5;
        const int col = idx & 31;
        xhS[idx] = xh[(size_t)(c * NT + t) * HIDDEN + j0 + col];
    }
    __syncthreads();

    const f32x4* hv4 = (const f32x4*)&hS[part * 68];
    const int w0 = tid;
    const int w1 = tid + 256;
    const int pe0 = 2 * tid + 4 * (tid >> 5);

    for (int t = 0; t < NT; ++t) {
        unsigned long long* rbuf = hxc + ((t + 1) & 1) * 512;
        unsigned long long* wbuf = hxc + (t & 1) * 512;
        const unsigned long long tok = (unsigned long long)(unsigned)t;
        unsigned long long a = __hip_atomic_load(&rbuf[w0], __ATOMIC_RELAXED, __HIP_MEMORY_SCOPE_AGENT);
        unsigned long long b = __hip_atomic_load(&rbuf[w1], __ATOMIC_RELAXED, __HIP_MEMORY_SCOPE_AGENT);
        while (((a & 0xffffull) != tok) | ((b & 0xffffull) != tok)) {
            __builtin_amdgcn_s_sleep(1);
            if ((a & 0xffffull) != tok)
                a = __hip_atomic_load(&rbuf[w0], __ATOMIC_RELAXED, __HIP_MEMORY_SCOPE_AGENT);
            if ((b & 0xffffull) != tok)
                b = __hip_atomic_load(&rbuf[w1], __ATOMIC_RELAXED, __HIP_MEMORY_SCOPE_AGENT);
        }
        *(float2*)&hS[pe0] = make_float2(__uint_as_float(((unsigned)(a >> 16) & 0xffffu) << 16),
                                         __uint_as_float(((unsigned)(a >> 32) & 0xffffu) << 16));
        *(float2*)&hS[pe0 + 544] = make_float2(__uint_as_float(((unsigned)(b >> 16) & 0xffffu) << 16),
                                               __uint_as_float(((unsigned)(b >> 32) & 0xffffu) << 16));
        __syncthreads();
        float a0 = 0.f, a1 = 0.f;
#pragma unroll
        for (int j = 0; j < 16; ++j) {
            const u32x4 w4 = wreg[j];
            const f32x4 h4 = hv4[j];
            a0 = fmaf(lo16f(w4.x), h4.x, a0); a1 = fmaf(hi16f(w4.x), h4.x, a1);
            a0 = fmaf(lo16f(w4.y), h4.y, a0); a1 = fmaf(hi16f(w4.y), h4.y, a1);
            a0 = fmaf(lo16f(w4.z), h4.z, a0); a1 = fmaf(hi16f(w4.z), h4.z, a1);
            a0 = fmaf(lo16f(w4.w), h4.w, a0); a1 = fmaf(hi16f(w4.w), h4.w, a1);
        }
        red[part * 33 + 2 * col2]     = a0;
        red[part * 33 + 2 * col2 + 1] = a1;
        __syncthreads();
        if (tid < RCOLS) {
            float s = 0.f;
#pragma unroll
            for (int p = 0; p < 16; ++p) s += red[p * 33 + tid];
            const float v = tanhf(xhS[t * RCOLS + tid] + s);
            const unsigned hb = (unsigned)bf16_bits(v);
            ((unsigned short*)hs)[(size_t)(c * NT + t) * HIDDEN + j0 + tid] = (unsigned short)hb;
            const unsigned pb = (unsigned)__shfl_xor((int)hb, 1, 64);
            if ((tid & 1) == 0) {
                const unsigned long long wv = (unsigned long long)(unsigned)(t + 1)
                                            | ((unsigned long long)hb << 16)
                                            | ((unsigned long long)pb << 32);
                __hip_atomic_store(&wbuf[m * 16 + (tid >> 1)], wv, __ATOMIC_RELAXED,
                                   __HIP_MEMORY_SCOPE_AGENT);
            }
        }
    }
}

// ---------------- y = hs @ Wt^T + b_y : 256x256, corrected 8-phase pipeline ----------------
// Invariant: all 4 halves of a buffer drained (vmcnt(0)) + barrier-crossed before that
// buffer's FIRST read phase (wave->region mapping touches all halves at first read).
// Stages: ph4-7 -> buf0's next tile; ph8 + next ph1-3 -> buf1's next. vmcnt(0) at
// ph4/ph8 entries drains exactly the 4 must-drain halves (stage follows the VMC), so
// no useful prefetch is destroyed. A-halves (hs, L2-hot) staged last.
__global__ __launch_bounds__(512, 2) void k_proj(const unsigned short* __restrict__ A,   // [2048][1024]
                                                 const unsigned short* __restrict__ Bt,  // [32000][1024]
                                                 const float* __restrict__ by,
                                                 float* __restrict__ C) {
    __shared__ unsigned short LDSu[8 * 8192];   // 128 KB: region = buf*4 + mat*2 + h
    const int tid = threadIdx.x;
    const int wid = tid >> 6;
    const int lane = tid & 63;
    const int lin = blockIdx.x;
    const int swz = (lin & 7) * 125 + (lin >> 3);
    const int mt = swz & 7, nt = swz >> 3;
    const int m0 = mt * 256, n0 = nt * 256;
    const int wr = wid >> 2, wc = wid & 3;       // 2 x 4 wave grid
    const int fr = lane & 15, fq = lane >> 4;

    f32x4 acc[8][4] = {};
    bf16x8 af[2][4][2];   // [mh-slot][q][ks]
    bf16x8 bg[2][2][2];   // [nh-slot][j][ks]

#define VMC0   asm volatile("s_waitcnt vmcnt(0)" ::: "memory")
#define LGKM0  do { asm volatile("s_waitcnt lgkmcnt(0)" ::: "memory"); \
                    __builtin_amdgcn_sched_barrier(0); } while (0)
#define BAR    __builtin_amdgcn_s_barrier()

#define STAGE_HALF(SRC, ROW0, KT, B_, MAT, H)                                             \
    do {                                                                                  \
        const unsigned short* g_ = (SRC) + (size_t)((ROW0) + (H) * 128) * HIDDEN + (KT) * 64; \
        _Pragma("unroll")                                                                 \
        for (int s2 = 0; s2 < 2; ++s2) {                                                  \
            const int ch_ = s2 * 512 + tid;                                               \
            const int lr_ = ch_ >> 3, sp_ = ch_ & 7;                                      \
            const int gs_ = sp_ ^ (lr_ & 7);                                              \
            __builtin_amdgcn_global_load_lds(                                             \
                (const AS1 unsigned*)(g_ + (size_t)lr_ * HIDDEN + gs_ * 8),               \
                (AS3 unsigned*)(LDSu + ((B_) * 4 + (MAT) * 2 + (H)) * 8192                \
                                + (s2 * 512 + wid * 64) * 8), 16, 0, 0);                  \
        }                                                                                 \
    } while (0)

#define READ_AF(B_, MH)                                                                   \
    do {                                                                                  \
        const unsigned short* r_ = LDSu + ((B_) * 4 + wr) * 8192;                         \
        _Pragma("unroll")                                                                 \
        for (int q_ = 0; q_ < 4; ++q_) {                                                  \
            const int lr_ = ((MH) * 4 + q_) * 16 + fr;                                    \
            _Pragma("unroll")                                                             \
            for (int ks_ = 0; ks_ < 2; ++ks_)                                             \
                af[MH][q_][ks_] = *(const bf16x8*)&r_[lr_ * 64 + (((ks_ * 4 + fq) ^ (fr & 7)) * 8)]; \
        }                                                                                 \
    } while (0)

#define READ_BG(B_, NH)                                                                   \
    do {                                                                                  \
        const unsigned short* r_ = LDSu + ((B_) * 4 + 2 + (wc >> 1)) * 8192;              \
        _Pragma("unroll")                                                                 \
        for (int j_ = 0; j_ < 2; ++j_) {                                                  \
            const int lr_ = (wc & 1) * 64 + ((NH) * 2 + j_) * 16 + fr;                    \
            _Pragma("unroll")                                                             \
            for (int ks_ = 0; ks_ < 2; ++ks_)                                             \
                bg[NH][j_][ks_] = *(const bf16x8*)&r_[lr_ * 64 + (((ks_ * 4 + fq) ^ (fr & 7)) * 8)]; \
        }                                                                                 \
    } while (0)

#define MFMA16(MH, NH)                                                                    \
    do {                                                                                  \
        __builtin_amdgcn_s_setprio(1);                                                    \
        _Pragma("unroll")                                                                 \
        for (int q_ = 0; q_ < 4; ++q_)                                                    \
            _Pragma("unroll")                                                             \
            for (int j_ = 0; j_ < 2; ++j_) {                                              \
                acc[(MH) * 4 + q_][(NH) * 2 + j_] = __builtin_amdgcn_mfma_f32_16x16x32_bf16( \
                    af[MH][q_][0], bg[NH][j_][0], acc[(MH) * 4 + q_][(NH) * 2 + j_], 0, 0, 0); \
                acc[(MH) * 4 + q_][(NH) * 2 + j_] = __builtin_amdgcn_mfma_f32_16x16x32_bf16( \
                    af[MH][q_][1], bg[NH][j_][1], acc[(MH) * 4 + q_][(NH) * 2 + j_], 0, 0, 0); \
            }                                                                             \
        __builtin_amdgcn_s_setprio(0);                                                    \
    } while (0)

    // prologue: tile0 (buf0: all 4 halves) + tile1's B0 (buf1); drain; barrier
    STAGE_HALF(Bt, n0, 0, 0, 1, 0);
    STAGE_HALF(Bt, n0, 0, 0, 1, 1);
    STAGE_HALF(A,  m0, 0, 0, 0, 0);
    STAGE_HALF(A,  m0, 0, 0, 0, 1);
    STAGE_HALF(Bt, n0, 1, 1, 1, 0);
    VMC0;
    BAR;

    for (int i = 0; i < 8; ++i) {
        const int t_b1cur = 2 * i + 1;    // buf1's current tile: finish staging ph1-3
        const int t_b0nxt = 2 * i + 2;    // buf0's next tile: stage ph4-7
        const int t_b1nxt = 2 * i + 3;    // buf1's next tile: B0 at ph8
        // ph1: read buf0 quadrant (0,0); stage buf1 B1
        READ_AF(0, 0); READ_BG(0, 0);
        STAGE_HALF(Bt, n0, t_b1cur, 1, 1, 1);
        BAR; LGKM0; MFMA16(0, 0); BAR;
        // ph2: read bg(0,1); stage buf1 A0
        READ_BG(0, 1);
        STAGE_HALF(A, m0, t_b1cur, 1, 0, 0);
        BAR; LGKM0; MFMA16(0, 1); BAR;
        // ph3: read af(0,1); stage buf1 A1   (buf0 reads complete at this close BAR)
        READ_AF(0, 1);
        STAGE_HALF(A, m0, t_b1cur, 1, 0, 1);
        BAR; LGKM0; MFMA16(1, 0); BAR;
        // ph4: drain buf1's 4 halves; stage buf0-next B0
        VMC0;
        if (t_b0nxt < 16) STAGE_HALF(Bt, n0, t_b0nxt, 0, 1, 0);
        BAR; MFMA16(1, 1); BAR;
        // ph5: read buf1 quadrant (0,0); stage buf0-next B1
        READ_AF(1, 0); READ_BG(1, 0);
        if (t_b0nxt < 16) STAGE_HALF(Bt, n0, t_b0nxt, 0, 1, 1);
        BAR; LGKM0; MFMA16(0, 0); BAR;
        // ph6: read bg(1,1); stage buf0-next A0
        READ_BG(1, 1);
        if (t_b0nxt < 16) STAGE_HALF(A, m0, t_b0nxt, 0, 0, 0);
        BAR; LGKM0; MFMA16(0, 1); BAR;
        // ph7: read af(1,1); stage buf0-next A1  (buf1 reads complete here)
        READ_AF(1, 1);
        if (t_b0nxt < 16) STAGE_HALF(A, m0, t_b0nxt, 0, 0, 1);
        BAR; LGKM0; MFMA16(1, 0); BAR;
        // ph8: drain buf0-next's 4 halves; stage buf1-next B0
        VMC0;
        if (t_b1nxt < 16) STAGE_HALF(Bt, n0, t_b1nxt, 1, 1, 0);
        BAR; MFMA16(1, 1); BAR;
    }

#undef VMC0
#undef LGKM0
#undef BAR
#undef STAGE_HALF
#undef READ_AF
#undef READ_BG
#undef MFMA16

#pragma unroll
    for (int ni = 0; ni < 4; ++ni) {
        const int col = n0 + wc * 64 + ni * 16 + fr;
        const float bias = by[col];
#pragma unroll
        for (int mi = 0; mi < 8; ++mi) {
            const int row = m0 + wr * 128 + mi * 16 + fq * 4;
            float* cp = C + (size_t)row * VOCAB + col;
            cp[0]                 = acc[mi][ni][0] + bias;
            cp[(size_t)VOCAB]     = acc[mi][ni][1] + bias;
            cp[(size_t)2 * VOCAB] = acc[mi][ni][2] + bias;
            cp[(size_t)3 * VOCAB] = acc[mi][ni][3] + bias;
        }
    }
}

extern "C" void kernel_launch(void* const* d_in, const int* in_sizes, int n_in,
                              void* d_out, int out_size, void* d_ws, size_t ws_size,
                              hipStream_t stream) {
    const int*   x   = (const int*)d_in[0];
    const float* emb = (const float*)d_in[1];
    const float* Wxh = (const float*)d_in[2];
    const float* Whh = (const float*)d_in[3];
    const float* bh  = (const float*)d_in[4];
    const float* Why = (const float*)d_in[5];
    const float* by  = (const float*)d_in[6];
    float* y = (float*)d_out;

    char* ws = (char*)d_ws;
    const size_t off_xh = 0;
    const size_t off_hx = off_xh + (size_t)NB * NT * HIDDEN * 4;
    const size_t off_hs = off_hx + (size_t)NCH * 2 * 512 * 8;
    const size_t off_wt = off_hs + (size_t)NB * NT * HIDDEN * 2;
    const size_t need   = off_wt + (size_t)VOCAB * HIDDEN * 2;
    if (ws_size < need) return;

    float* xh = (float*)(ws + off_xh);
    unsigned long long* hx = (unsigned long long*)(ws + off_hx);
    __hip_bfloat16* hs = (__hip_bfloat16*)(ws + off_hs);
    __hip_bfloat16* Wt = (__hip_bfloat16*)(ws + off_wt);

    k_xh<<<dim3((NB * NT) / XH_ROWS), 256, 0, stream>>>(x, emb, Wxh, bh, xh);
    k_fused<<<dim3(NBLK_REC + NBLK_TR), 256, 0, stream>>>(Whh, xh, hx, hs, Why, Wt);
    k_proj<<<dim3((2048 / 256) * (VOCAB / 256)), 512, 0, stream>>>((const unsigned short*)hs,
                                                                   (const unsigned short*)Wt, by, y);
}